// Round 8
// baseline (363.141 us; speedup 1.0000x reference)
//
#include <hip/hip_runtime.h>

#define N_NODES 50000
#define N_EDGES 640000
#define F 128
#define DFF 512
#define NB 196   // ceil(N_NODES/256)

using u32 = unsigned int;
using u16 = unsigned short;

typedef __bf16 bf16x8 __attribute__((ext_vector_type(8)));
typedef float f32x4 __attribute__((ext_vector_type(4)));
typedef float f32x2 __attribute__((ext_vector_type(2)));

__device__ __forceinline__ float bf2f(u16 u) {
    return __uint_as_float(((u32)u) << 16);
}
__device__ __forceinline__ float blo(u32 p) { return __uint_as_float(p << 16); }
__device__ __forceinline__ float bhi(u32 p) { return __uint_as_float(p & 0xffff0000u); }
__device__ __forceinline__ u16 f2bf(float f) {
    u32 u = __float_as_uint(f);
    u += 0x7fffu + ((u >> 16) & 1u);   // RNE
    return (u16)(u >> 16);
}
__device__ __forceinline__ u32 pack2(float a, float b) {
    return (u32)f2bf(a) | ((u32)f2bf(b) << 16);
}

// ---------------- fused prep: feat->bf16 + weights->bf16^T + degree histogram ----------
#define FEAT_UNITS (N_NODES * F / 4)   // 1,600,000 float4 units
#define PH_TOTAL (FEAT_UNITS + 180224 + N_EDGES)
__global__ void k_prep(const float* __restrict__ feat, u16* __restrict__ featb,
                       const float* __restrict__ Wq, const float* __restrict__ Wk,
                       const float* __restrict__ Wv, const float* __restrict__ W1,
                       const float* __restrict__ W2, u16* __restrict__ WT,
                       const int* __restrict__ dst, int* __restrict__ cnt) {
    int idx = blockIdx.x * 256 + threadIdx.x;
    if (idx < FEAT_UNITS) {
        float4 v = reinterpret_cast<const float4*>(feat)[idx];
        uint2 p;
        p.x = pack2(v.x, v.y);
        p.y = pack2(v.z, v.w);
        reinterpret_cast<uint2*>(featb)[idx] = p;
        return;
    }
    int wi = idx - FEAT_UNITS;
    if (wi < 180224) {
        if (wi < 49152) {
            int mi = wi >> 14;
            int local = wi & 16383;
            const float* W = (mi == 0) ? Wq : ((mi == 1) ? Wk : Wv);
            int n = local >> 7, k = local & 127;
            WT[wi] = f2bf(W[(size_t)k * 128 + n]);
        } else if (wi < 114688) {
            int local = wi - 49152;
            int n = local >> 7, k = local & 127;
            WT[wi] = f2bf(W1[(size_t)k * 512 + n]);
        } else {
            int local = wi - 114688;
            int n = local >> 9, k = local & 511;
            WT[wi] = f2bf(W2[(size_t)k * 128 + n]);
        }
        return;
    }
    int e = wi - 180224;
    if (e < N_EDGES) atomicAdd(&cnt[dst[e]], 1);
}

// ---------------- CSR build ----------------
__global__ void k_bsum(const int* __restrict__ counts, int* __restrict__ bsum) {
    int i = blockIdx.x * 256 + threadIdx.x;
    int v = (i < N_NODES) ? counts[i] : 0;
#pragma unroll
    for (int off = 32; off >= 1; off >>= 1) v += __shfl_xor(v, off, 64);
    __shared__ int ws[4];
    int lane = threadIdx.x & 63, wid = threadIdx.x >> 6;
    if (lane == 0) ws[wid] = v;
    __syncthreads();
    if (threadIdx.x == 0) bsum[blockIdx.x] = ws[0] + ws[1] + ws[2] + ws[3];
}

// fused: block-scan of bsum (196 entries) in-LDS + per-chunk scan of counts
__global__ void k_bfill(const int* __restrict__ counts, const int* __restrict__ bsum,
                        int* __restrict__ row_ptr) {
    int b = blockIdx.x, t = threadIdx.x;
    int lane = t & 63, wid = t >> 6;
    __shared__ int ws[4];
    __shared__ int sboff[256];

    int bv = (t < NB) ? bsum[t] : 0;
    int bincl = bv;
#pragma unroll
    for (int off = 1; off < 64; off <<= 1) {
        int u = __shfl_up(bincl, off, 64);
        if (lane >= off) bincl += u;
    }
    if (lane == 63) ws[wid] = bincl;
    __syncthreads();
    int bwo = 0;
#pragma unroll
    for (int j = 0; j < 4; ++j) if (j < wid) bwo += ws[j];
    sboff[t] = bwo + bincl - bv;
    __syncthreads();
    const int boff = sboff[b];

    int i = b * 256 + t;
    int v = (i < N_NODES) ? counts[i] : 0;
    int incl = v;
#pragma unroll
    for (int off = 1; off < 64; off <<= 1) {
        int u = __shfl_up(incl, off, 64);
        if (lane >= off) incl += u;
    }
    if (lane == 63) ws[wid] = incl;
    __syncthreads();
    int wo = 0;
#pragma unroll
    for (int j = 0; j < 4; ++j) if (j < wid) wo += ws[j];
    if (i < N_NODES) row_ptr[i] = boff + wo + incl - v;
    if (i == 0) row_ptr[N_NODES] = N_EDGES;
}

__global__ void k_fill(const int* __restrict__ src, const int* __restrict__ dst,
                       const int* __restrict__ row_ptr, int* __restrict__ fill,
                       int* __restrict__ csr_src) {
    int e = blockIdx.x * 256 + threadIdx.x;
    if (e < N_EDGES) {
        int d = dst[e];
        int pos = row_ptr[d] + atomicAdd(&fill[d], 1);
        csr_src[pos] = src[e];
    }
}

// ---------------- MFMA GEMM (qkv only): 128x128 tile, K-chunk 64, XOR-swizzled LDS ------
// EPI 0: qkv record per node = 128 u32 words (512 B):
//        words 0..63: q as bf16 pairs; word 64+i bytes = [k(2i),k(2i+1),v(2i),v(2i+1)] fp8
template <int EPI>
__global__ __launch_bounds__(256) void k_mm(
    const u16* __restrict__ A, int lda,
    const u16* __restrict__ BT,
    void* __restrict__ Cv, int ldc,
    int K,
    const float* __restrict__ bias,
    const float* __restrict__ prelu,
    const u16* __restrict__ resid,
    const float* __restrict__ g,
    const float* __restrict__ bb)
{
    __shared__ u16 smem[17408];
    u16* sA = smem;                 // 128 rows x 64 u16 (swizzled)
    u16* sB = smem + 128 * 64;
    u16* sC = smem;                 // epilogue overlay

    const int t = threadIdx.x;
    const int w = t >> 6;
    const int lane = t & 63;
    const int ln = lane & 15, q4 = lane >> 4;
    const int row0 = blockIdx.x * 128;
    const int cb = blockIdx.y * 128;

    f32x4 acc[2][8];
#pragma unroll
    for (int mt = 0; mt < 2; ++mt)
#pragma unroll
        for (int nt = 0; nt < 8; ++nt)
            acc[mt][nt] = (f32x4){0.f, 0.f, 0.f, 0.f};

    uint4 pa[4], pb[4];
#define LOAD_A(kc)                                                             \
    {                                                                          \
        _Pragma("unroll") for (int i = 0; i < 4; ++i) {                        \
            int u = i * 256 + t, r = u >> 3, k8 = (u & 7) * 8;                 \
            int row = row0 + r;                                                \
            uint4 val = make_uint4(0, 0, 0, 0);                                \
            if (row < N_NODES)                                                 \
                val = *reinterpret_cast<const uint4*>(A + (size_t)row * lda + (kc) + k8); \
            pa[i] = val;                                                       \
        }                                                                      \
    }
#define LOAD_B(kc)                                                             \
    {                                                                          \
        _Pragma("unroll") for (int i = 0; i < 4; ++i) {                        \
            int u = i * 256 + t, r = u >> 3, k8 = (u & 7) * 8;                 \
            pb[i] = *reinterpret_cast<const uint4*>(BT + (size_t)(cb + r) * K + (kc) + k8); \
        }                                                                      \
    }

    LOAD_A(0);
    LOAD_B(0);

    for (int kc = 0; kc < K; kc += 64) {
#pragma unroll
        for (int i = 0; i < 4; ++i) {
            int u = i * 256 + t, r = u >> 3, gi = u & 7;
            int off = (r * 8 + (gi ^ (r & 7))) * 8;
            *reinterpret_cast<uint4*>(&sA[off]) = pa[i];
            *reinterpret_cast<uint4*>(&sB[off]) = pb[i];
        }
        __syncthreads();
        if (kc + 64 < K) {
            LOAD_A(kc + 64);
            LOAD_B(kc + 64);
        }
#pragma unroll
        for (int ks = 0; ks < 2; ++ks) {
            const int gsw = ks * 4 + q4;
            const int rA0 = w * 32 + ln;
            const int rA1 = rA0 + 16;
            bf16x8 a0 = *reinterpret_cast<const bf16x8*>(&sA[(rA0 * 8 + (gsw ^ (rA0 & 7))) * 8]);
            bf16x8 a1 = *reinterpret_cast<const bf16x8*>(&sA[(rA1 * 8 + (gsw ^ (rA1 & 7))) * 8]);
#pragma unroll
            for (int nt = 0; nt < 8; ++nt) {
                const int rB = nt * 16 + ln;
                bf16x8 b = *reinterpret_cast<const bf16x8*>(&sB[(rB * 8 + (gsw ^ (rB & 7))) * 8]);
                acc[0][nt] = __builtin_amdgcn_mfma_f32_16x16x32_bf16(a0, b, acc[0][nt], 0, 0, 0);
                acc[1][nt] = __builtin_amdgcn_mfma_f32_16x16x32_bf16(a1, b, acc[1][nt], 0, 0, 0);
            }
        }
        __syncthreads();
    }
#undef LOAD_A
#undef LOAD_B

    {
#pragma unroll
        for (int mt = 0; mt < 2; ++mt)
#pragma unroll
            for (int nt = 0; nt < 8; ++nt)
#pragma unroll
                for (int j = 0; j < 4; ++j) {
                    float x = acc[mt][nt][j];
                    sC[(w * 32 + mt * 16 + q4 * 4 + j) * 136 + nt * 16 + ln] = f2bf(x);
                }
        __syncthreads();
        if (EPI == 0 && cb != 0) {
            // pack K (cb==128, even u16) or V (cb==256, odd u16) as fp8 e4m3 pairs
            u16* C = (u16*)Cv;
            const u32 vflag = (cb == 256) ? 1u : 0u;
#pragma unroll
            for (int i = 0; i < 32; ++i) {   // 128 rows * 64 pairs = 8192 units
                int u = i * 256 + t;
                int r = u >> 6, p = u & 63;
                int row = row0 + r;
                if (row < N_NODES) {
                    u32 pair = *reinterpret_cast<const u32*>(&sC[r * 136 + p * 2]);
                    int packed = __builtin_amdgcn_cvt_pk_fp8_f32(blo(pair), bhi(pair), 0, false);
                    C[(u32)row * 256u + 128u + (u32)p * 2u + vflag] = (u16)(packed & 0xffff);
                }
            }
        } else {
            u16* C = (u16*)Cv;
#pragma unroll
            for (int i = 0; i < 8; ++i) {
                int u = i * 256 + t;
                int r = u >> 4, c8 = (u & 15) * 8;
                int row = row0 + r;
                if (row < N_NODES) {
                    uint4 val = *reinterpret_cast<const uint4*>(&sC[r * 136 + c8]);
                    *reinterpret_cast<uint4*>(&C[(size_t)row * ldc + cb + c8]) = val;
                }
            }
        }
    }
}

// ---------------- fused FFN: out = LN(rst + PReLU(rst@W1+b1)@W2 + b2) ----------------
// One block per 128 rows. sA = rst tile (bf16, 16-granule XOR swizzle, resident).
// Per 128-col DFF chunk: GEMM1 from sA + W1T(L2-direct B-frags) -> acc1;
// bias+PReLU+f2bf -> sH (wave-private rows, no barriers); GEMM2 accumulates acc2.
// K-order identical to the old mm1->mm2 chain => bitwise-identical output.
__global__ __launch_bounds__(256) void k_ffn(
    const u16* __restrict__ rstb,     // [N][128] bf16
    const u16* __restrict__ W1T,      // [512][128] bf16
    const u16* __restrict__ W2T,      // [128][512] bf16
    const float* __restrict__ b1,
    const float* __restrict__ prelu,
    const float* __restrict__ b2,
    const float* __restrict__ g,
    const float* __restrict__ bb,
    float* __restrict__ out)
{
    __shared__ u16 sA[16384];   // 128 x 128, swizzled
    __shared__ u16 sH[16384];   // 128 x 128, swizzled, wave-private rows

    const int t = threadIdx.x;
    const int w = t >> 6;
    const int lane = t & 63;
    const int ln = lane & 15, q4 = lane >> 4;
    const int row0 = blockIdx.x * 128;

    // stage sA: row r, granule gi (8 u16) -> (r*16 + (gi ^ (r&15))) * 8
#pragma unroll
    for (int i = 0; i < 8; ++i) {
        int u = i * 256 + t, r = u >> 4, gi = u & 15;
        int row = row0 + r;
        uint4 val = make_uint4(0, 0, 0, 0);
        if (row < N_NODES)
            val = *reinterpret_cast<const uint4*>(rstb + (size_t)row * 128 + gi * 8);
        *reinterpret_cast<uint4*>(&sA[(r * 16 + (gi ^ (r & 15))) * 8]) = val;
    }
    __syncthreads();

    const int rA0 = w * 32 + ln;
    const int rA1 = rA0 + 16;

    f32x4 acc2[2][8];
#pragma unroll
    for (int mt = 0; mt < 2; ++mt)
#pragma unroll
        for (int nt = 0; nt < 8; ++nt)
            acc2[mt][nt] = (f32x4){0.f, 0.f, 0.f, 0.f};

    for (int c = 0; c < 4; ++c) {
        // GEMM1: acc1 = sA @ W1T[c*128 .. c*128+127]
        f32x4 acc1[2][8];
#pragma unroll
        for (int mt = 0; mt < 2; ++mt)
#pragma unroll
            for (int nt = 0; nt < 8; ++nt)
                acc1[mt][nt] = (f32x4){0.f, 0.f, 0.f, 0.f};
#pragma unroll
        for (int ks = 0; ks < 4; ++ks) {
            const int gsw = ks * 4 + q4;
            bf16x8 a0 = *reinterpret_cast<const bf16x8*>(&sA[(rA0 * 16 + (gsw ^ (rA0 & 15))) * 8]);
            bf16x8 a1 = *reinterpret_cast<const bf16x8*>(&sA[(rA1 * 16 + (gsw ^ (rA1 & 15))) * 8]);
#pragma unroll
            for (int nt = 0; nt < 8; ++nt) {
                bf16x8 b = *reinterpret_cast<const bf16x8*>(
                    W1T + (size_t)(c * 128 + nt * 16 + ln) * 128 + ks * 32 + q4 * 8);
                acc1[0][nt] = __builtin_amdgcn_mfma_f32_16x16x32_bf16(a0, b, acc1[0][nt], 0, 0, 0);
                acc1[1][nt] = __builtin_amdgcn_mfma_f32_16x16x32_bf16(a1, b, acc1[1][nt], 0, 0, 0);
            }
        }
        // bias + PReLU -> bf16 -> sH (wave-private rows; in-wave LDS ordering suffices)
#pragma unroll
        for (int mt = 0; mt < 2; ++mt)
#pragma unroll
            for (int nt = 0; nt < 8; ++nt) {
                const int col = nt * 16 + ln;
                const float bsv = b1[c * 128 + col];
                const float prv = prelu[c * 128 + col];
                const int gi = col >> 3;
#pragma unroll
                for (int j = 0; j < 4; ++j) {
                    float x = acc1[mt][nt][j] + bsv;
                    x = (x >= 0.f) ? x : prv * x;
                    const int row = w * 32 + mt * 16 + q4 * 4 + j;
                    sH[(row * 16 + (gi ^ (row & 15))) * 8 + (col & 7)] = f2bf(x);
                }
            }
        // GEMM2: acc2 += sH @ W2T[:, c*128 .. c*128+127]
#pragma unroll
        for (int ks = 0; ks < 4; ++ks) {
            const int gsw = ks * 4 + q4;
            bf16x8 h0 = *reinterpret_cast<const bf16x8*>(&sH[(rA0 * 16 + (gsw ^ (rA0 & 15))) * 8]);
            bf16x8 h1 = *reinterpret_cast<const bf16x8*>(&sH[(rA1 * 16 + (gsw ^ (rA1 & 15))) * 8]);
#pragma unroll
            for (int nt = 0; nt < 8; ++nt) {
                bf16x8 b = *reinterpret_cast<const bf16x8*>(
                    W2T + (size_t)(nt * 16 + ln) * 512 + c * 128 + ks * 32 + q4 * 8);
                acc2[0][nt] = __builtin_amdgcn_mfma_f32_16x16x32_bf16(h0, b, acc2[0][nt], 0, 0, 0);
                acc2[1][nt] = __builtin_amdgcn_mfma_f32_16x16x32_bf16(h1, b, acc2[1][nt], 0, 0, 0);
            }
        }
    }

    // epilogue: + b2 + resid(sA) + row LayerNorm, fp32 out
    float bs[8], gv[8], bv[8];
#pragma unroll
    for (int nt = 0; nt < 8; ++nt) {
        int col = nt * 16 + ln;
        bs[nt] = b2[col];
        gv[nt] = g[col];
        bv[nt] = bb[col];
    }
#pragma unroll
    for (int mt = 0; mt < 2; ++mt)
#pragma unroll
        for (int j = 0; j < 4; ++j) {
            const int lrow = w * 32 + mt * 16 + q4 * 4 + j;
            const int row = row0 + lrow;
            const bool ok = row < N_NODES;
            float vals[8];
            float s = 0.f, ss = 0.f;
#pragma unroll
            for (int nt = 0; nt < 8; ++nt) {
                const int col = nt * 16 + ln;
                const int gi = col >> 3;
                float res = bf2f(sA[(lrow * 16 + (gi ^ (lrow & 15))) * 8 + (col & 7)]);
                float x = acc2[mt][nt][j] + bs[nt] + res;
                vals[nt] = x;
                s += x; ss += x * x;
            }
            s += __shfl_xor(s, 8, 16); ss += __shfl_xor(ss, 8, 16);
            s += __shfl_xor(s, 4, 16); ss += __shfl_xor(ss, 4, 16);
            s += __shfl_xor(s, 2, 16); ss += __shfl_xor(ss, 2, 16);
            s += __shfl_xor(s, 1, 16); ss += __shfl_xor(ss, 1, 16);
            float mu = s * (1.f / 128.f);
            float var = ss * (1.f / 128.f) - mu * mu;
            float rs = rsqrtf(var + 1e-5f);
            if (ok) {
#pragma unroll
                for (int nt = 0; nt < 8; ++nt)
                    out[(size_t)row * 128 + nt * 16 + ln] =
                        (vals[nt] - mu) * rs * gv[nt] + bv[nt];
            }
        }
}

// ---------------- attention: 1 wave/node, fp8 K/V, one u32 load/edge ----------
// Record: 128 u32/node. q words 0..63 bf16-pairs; word 64+lane = [k0 k1 v0 v1] fp8.
// Pipeline: csr 2-groups-ahead, A/B ping-pong.
__global__ __launch_bounds__(256) void k_attn(
    const u32* __restrict__ Q32, const float* __restrict__ feat,
    const int* __restrict__ row_ptr, const int* __restrict__ csr_src,
    const float* __restrict__ g, const float* __restrict__ bb,
    u16* __restrict__ rstb)
{
    const int w = threadIdx.x >> 6;
    const int lane = threadIdx.x & 63;
    const int n = blockIdx.x * 4 + w;
    if (n >= N_NODES) return;
    const float scale = 0.08838834764831845f;  // 1/sqrt(128)

    const u32 qp = Q32[(u32)n * 128u + (u32)lane];
    const float q0 = blo(qp), q1 = bhi(qp);
    const int e0 = row_ptr[n], e1 = row_ptr[n + 1];
    const u32 kvlane = 64u + (u32)lane;

    float l = 0.f, a0 = 0.f, a1 = 0.f;

#define LD4(S, KV)                                                                      \
    {                                                                                   \
        KV[0] = Q32[(u32)(S).x * 128u + kvlane];                                        \
        KV[1] = Q32[(u32)(S).y * 128u + kvlane];                                        \
        KV[2] = Q32[(u32)(S).z * 128u + kvlane];                                        \
        KV[3] = Q32[(u32)(S).w * 128u + kvlane];                                        \
    }
#define CG(KV)                                                                          \
    {                                                                                   \
        f32x2 k0 = __builtin_amdgcn_cvt_pk_f32_fp8((int)KV[0], false);                  \
        f32x2 k1 = __builtin_amdgcn_cvt_pk_f32_fp8((int)KV[1], false);                  \
        f32x2 k2 = __builtin_amdgcn_cvt_pk_f32_fp8((int)KV[2], false);                  \
        f32x2 k3 = __builtin_amdgcn_cvt_pk_f32_fp8((int)KV[3], false);                  \
        float p0 = k0.x * q0 + k0.y * q1;                                               \
        float p1 = k1.x * q0 + k1.y * q1;                                               \
        float p2 = k2.x * q0 + k2.y * q1;                                               \
        float p3 = k3.x * q0 + k3.y * q1;                                               \
        p0 += __shfl_xor(p0, 4, 8); p1 += __shfl_xor(p1, 4, 8);                         \
        p2 += __shfl_xor(p2, 4, 8); p3 += __shfl_xor(p3, 4, 8);                         \
        p0 += __shfl_xor(p0, 2, 8); p1 += __shfl_xor(p1, 2, 8);                         \
        p2 += __shfl_xor(p2, 2, 8); p3 += __shfl_xor(p3, 2, 8);                         \
        p0 += __shfl_xor(p0, 1, 8); p1 += __shfl_xor(p1, 1, 8);                         \
        p2 += __shfl_xor(p2, 1, 8); p3 += __shfl_xor(p3, 1, 8);                         \
        float ea = __expf(p0 * scale), eb = __expf(p1 * scale);                         \
        float ec = __expf(p2 * scale), ed = __expf(p3 * scale);                         \
        l += (ea + eb) + (ec + ed);                                                     \
        f32x2 v0 = __builtin_amdgcn_cvt_pk_f32_fp8((int)KV[0], true);                   \
        f32x2 v1 = __builtin_amdgcn_cvt_pk_f32_fp8((int)KV[1], true);                   \
        f32x2 v2 = __builtin_amdgcn_cvt_pk_f32_fp8((int)KV[2], true);                   \
        f32x2 v3 = __builtin_amdgcn_cvt_pk_f32_fp8((int)KV[3], true);                   \
        a0 += ea * v0.x + eb * v1.x + ec * v2.x + ed * v3.x;                            \
        a1 += ea * v0.y + eb * v1.y + ec * v2.y + ed * v3.y;                            \
    }

    int e = e0;
    int rem = e1 - e0;
    {
        int4 sA, sB;
        u32 kvA[4], kvB[4];
        if (rem >= 4) {
            sA = *reinterpret_cast<const int4*>(csr_src + e);
            LD4(sA, kvA);
            if (rem >= 8) {
                sB = *reinterpret_cast<const int4*>(csr_src + e + 4);
                while (true) {
                    if (rem >= 12) sA = *reinterpret_cast<const int4*>(csr_src + e + 8);
                    LD4(sB, kvB);
                    CG(kvA);
                    e += 4; rem -= 4;
                    if (rem < 8) { CG(kvB); e += 4; rem -= 4; break; }
                    if (rem >= 12) sB = *reinterpret_cast<const int4*>(csr_src + e + 8);
                    LD4(sA, kvA);
                    CG(kvB);
                    e += 4; rem -= 4;
                    if (rem < 8) { CG(kvA); e += 4; rem -= 4; break; }
                }
            } else {
                CG(kvA);
                e += 4; rem -= 4;
            }
        }
    }
    // tail: 0..3 edges
    for (; e < e1; ++e) {
        int s0 = csr_src[e];
        u32 kv = Q32[(u32)s0 * 128u + kvlane];
        f32x2 kf = __builtin_amdgcn_cvt_pk_f32_fp8((int)kv, false);
        float p0 = kf.x * q0 + kf.y * q1;
        p0 += __shfl_xor(p0, 4, 8);
        p0 += __shfl_xor(p0, 2, 8);
        p0 += __shfl_xor(p0, 1, 8);
        float ea = __expf(p0 * scale);
        f32x2 vf = __builtin_amdgcn_cvt_pk_f32_fp8((int)kv, true);
        l += ea;
        a0 += ea * vf.x;
        a1 += ea * vf.y;
    }
#undef LD4
#undef CG

    float inv = (l > 0.f) ? 1.f / l : 0.f;   // deg-0 node -> 0
    const int c2 = lane * 2;
    const float2 fr = *reinterpret_cast<const float2*>(feat + (size_t)n * 128 + c2);
    float x0 = a0 * inv + fr.x;
    float x1 = a1 * inv + fr.y;

    float sum = x0 + x1, sq = x0 * x0 + x1 * x1;
#pragma unroll
    for (int off = 32; off >= 1; off >>= 1) {
        sum += __shfl_xor(sum, off, 64);
        sq += __shfl_xor(sq, off, 64);
    }
    float mu = sum * (1.f / 128.f);
    float var = sq * (1.f / 128.f) - mu * mu;
    float rs = rsqrtf(var + 1e-5f);
    float y0 = (x0 - mu) * rs * g[c2] + bb[c2];
    float y1 = (x1 - mu) * rs * g[c2 + 1] + bb[c2 + 1];
    reinterpret_cast<u32*>(rstb)[(size_t)n * 64 + lane] = pack2(y0, y1);
}

extern "C" void kernel_launch(void* const* d_in, const int* in_sizes, int n_in,
                              void* d_out, int out_size, void* d_ws, size_t ws_size,
                              hipStream_t stream)
{
    const float* feat = (const float*)d_in[0];
    const int* src    = (const int*)d_in[1];
    const int* dst    = (const int*)d_in[2];
    const float* Wq   = (const float*)d_in[3];
    const float* Wk   = (const float*)d_in[4];
    const float* Wv   = (const float*)d_in[5];
    const float* ln_g = (const float*)d_in[6];
    const float* ln_b = (const float*)d_in[7];
    const float* W1   = (const float*)d_in[8];
    const float* b1   = (const float*)d_in[9];
    const float* pa   = (const float*)d_in[10];
    const float* W2   = (const float*)d_in[11];
    const float* b2   = (const float*)d_in[12];

    u16* qkv   = (u16*)d_ws;                           // 50000*256 u16 used (region reserves 384)
    u16* h     = qkv + (size_t)N_NODES * 384;          // region kept for layout stability
    u16* featb = h;                                    // 50000*128, dead before ffn
    u16* rstb  = h + (size_t)N_NODES * 512;            // 50000*128
    u16* WT    = rstb + (size_t)N_NODES * 128;         // 180224
    u16* BqkvT = WT;
    u16* W1T   = WT + 49152;
    u16* W2T   = WT + 114688;
    int* counts  = (int*)(WT + 180224);
    int* fill    = counts + N_NODES;
    int* row_ptr = fill + N_NODES;
    int* csr_src = row_ptr + N_NODES + 1;
    int* bsum    = csr_src + N_EDGES;

    // zero counts+fill first, then fused prep+hist
    hipMemsetAsync(counts, 0, sizeof(int) * 2 * N_NODES, stream);
    k_prep<<<(PH_TOTAL + 255) / 256, 256, 0, stream>>>(
        feat, featb, Wq, Wk, Wv, W1, W2, WT, dst, counts);

    // CSR: bsum -> fused scan+fill of row_ptr -> edge fill
    k_bsum<<<NB, 256, 0, stream>>>(counts, bsum);
    k_bfill<<<NB, 256, 0, stream>>>(counts, bsum, row_ptr);
    k_fill<<<(N_EDGES + 255) / 256, 256, 0, stream>>>(src, dst, row_ptr, fill, csr_src);

    const int MBK = (N_NODES + 127) / 128;   // 391

    dim3 gqkv(MBK, 3);
    k_mm<0><<<gqkv, 256, 0, stream>>>(featb, 128, BqkvT, qkv, 256, 128,
                                      nullptr, nullptr, nullptr, nullptr, nullptr);

    k_attn<<<(N_NODES + 3) / 4, 256, 0, stream>>>((const u32*)qkv, feat, row_ptr, csr_src,
                                                  ln_g, ln_b, rstb);

    k_ffn<<<MBK, 256, 0, stream>>>(rstb, W1T, W2T, b1, pa, b2, ln_g, ln_b,
                                   (float*)d_out);
}

// Round 9
// 362.665 us; speedup vs baseline: 1.0013x; 1.0013x over previous
//
#include <hip/hip_runtime.h>

#define N_NODES 50000
#define N_EDGES 640000
#define F 128
#define DFF 512
#define NB 196   // ceil(N_NODES/256)

using u32 = unsigned int;
using u16 = unsigned short;

typedef __bf16 bf16x8 __attribute__((ext_vector_type(8)));
typedef float f32x4 __attribute__((ext_vector_type(4)));
typedef float f32x2 __attribute__((ext_vector_type(2)));

__device__ __forceinline__ float bf2f(u16 u) {
    return __uint_as_float(((u32)u) << 16);
}
__device__ __forceinline__ float blo(u32 p) { return __uint_as_float(p << 16); }
__device__ __forceinline__ float bhi(u32 p) { return __uint_as_float(p & 0xffff0000u); }
__device__ __forceinline__ u16 f2bf(float f) {
    u32 u = __float_as_uint(f);
    u += 0x7fffu + ((u >> 16) & 1u);   // RNE
    return (u16)(u >> 16);
}
__device__ __forceinline__ u32 pack2(float a, float b) {
    return (u32)f2bf(a) | ((u32)f2bf(b) << 16);
}

// ---------------- fused prep: feat->bf16 + weights + degree histogram ----------------
// W1/W2 are emitted FRAG-LINEAR for k_ffn: for (c,ks,nt) the 64 lanes' bf16x8
// fragments are contiguous -> each wave B-load is one coalesced 1KB read.
//   W1F[((c*4+ks)*8+nt)*512 + lane*8 + j] = W1[ks*32+(lane>>4)*8+j][c*128+nt*16+(lane&15)]
//   W2F[((c*4+ks)*8+nt)*512 + lane*8 + j] = W2[c*128+ks*32+(lane>>4)*8+j][nt*16+(lane&15)]
#define FEAT_UNITS (N_NODES * F / 4)   // 1,600,000 float4 units
#define PH_TOTAL (FEAT_UNITS + 180224 + N_EDGES)
__global__ void k_prep(const float* __restrict__ feat, u16* __restrict__ featb,
                       const float* __restrict__ Wq, const float* __restrict__ Wk,
                       const float* __restrict__ Wv, const float* __restrict__ W1,
                       const float* __restrict__ W2, u16* __restrict__ WT,
                       const int* __restrict__ dst, int* __restrict__ cnt) {
    int idx = blockIdx.x * 256 + threadIdx.x;
    if (idx < FEAT_UNITS) {
        float4 v = reinterpret_cast<const float4*>(feat)[idx];
        uint2 p;
        p.x = pack2(v.x, v.y);
        p.y = pack2(v.z, v.w);
        reinterpret_cast<uint2*>(featb)[idx] = p;
        return;
    }
    int wi = idx - FEAT_UNITS;
    if (wi < 180224) {
        if (wi < 49152) {
            int mi = wi >> 14;
            int local = wi & 16383;
            const float* W = (mi == 0) ? Wq : ((mi == 1) ? Wk : Wv);
            int n = local >> 7, k = local & 127;
            WT[wi] = f2bf(W[(size_t)k * 128 + n]);
        } else if (wi < 114688) {
            int fi = wi - 49152;           // frag-linear W1
            int j = fi & 7;
            int lane = (fi >> 3) & 63;
            int u = fi >> 9;               // 0..127
            int nt = u & 7, ks = (u >> 3) & 3, c = u >> 5;
            int n = c * 128 + nt * 16 + (lane & 15);
            int k = ks * 32 + (lane >> 4) * 8 + j;
            WT[wi] = f2bf(W1[(size_t)k * 512 + n]);
        } else {
            int fi = wi - 114688;          // frag-linear W2
            int j = fi & 7;
            int lane = (fi >> 3) & 63;
            int u = fi >> 9;               // 0..127
            int nt = u & 7, ks = (u >> 3) & 3, c = u >> 5;
            int n = nt * 16 + (lane & 15);
            int k = c * 128 + ks * 32 + (lane >> 4) * 8 + j;
            WT[wi] = f2bf(W2[(size_t)k * 128 + n]);
        }
        return;
    }
    int e = wi - 180224;
    if (e < N_EDGES) atomicAdd(&cnt[dst[e]], 1);
}

// ---------------- CSR build ----------------
__global__ void k_bsum(const int* __restrict__ counts, int* __restrict__ bsum) {
    int i = blockIdx.x * 256 + threadIdx.x;
    int v = (i < N_NODES) ? counts[i] : 0;
#pragma unroll
    for (int off = 32; off >= 1; off >>= 1) v += __shfl_xor(v, off, 64);
    __shared__ int ws[4];
    int lane = threadIdx.x & 63, wid = threadIdx.x >> 6;
    if (lane == 0) ws[wid] = v;
    __syncthreads();
    if (threadIdx.x == 0) bsum[blockIdx.x] = ws[0] + ws[1] + ws[2] + ws[3];
}

// fused: block-scan of bsum (196 entries) in-LDS + per-chunk scan of counts
__global__ void k_bfill(const int* __restrict__ counts, const int* __restrict__ bsum,
                        int* __restrict__ row_ptr) {
    int b = blockIdx.x, t = threadIdx.x;
    int lane = t & 63, wid = t >> 6;
    __shared__ int ws[4];
    __shared__ int sboff[256];

    int bv = (t < NB) ? bsum[t] : 0;
    int bincl = bv;
#pragma unroll
    for (int off = 1; off < 64; off <<= 1) {
        int u = __shfl_up(bincl, off, 64);
        if (lane >= off) bincl += u;
    }
    if (lane == 63) ws[wid] = bincl;
    __syncthreads();
    int bwo = 0;
#pragma unroll
    for (int j = 0; j < 4; ++j) if (j < wid) bwo += ws[j];
    sboff[t] = bwo + bincl - bv;
    __syncthreads();
    const int boff = sboff[b];

    int i = b * 256 + t;
    int v = (i < N_NODES) ? counts[i] : 0;
    int incl = v;
#pragma unroll
    for (int off = 1; off < 64; off <<= 1) {
        int u = __shfl_up(incl, off, 64);
        if (lane >= off) incl += u;
    }
    if (lane == 63) ws[wid] = incl;
    __syncthreads();
    int wo = 0;
#pragma unroll
    for (int j = 0; j < 4; ++j) if (j < wid) wo += ws[j];
    if (i < N_NODES) row_ptr[i] = boff + wo + incl - v;
    if (i == 0) row_ptr[N_NODES] = N_EDGES;
}

__global__ void k_fill(const int* __restrict__ src, const int* __restrict__ dst,
                       const int* __restrict__ row_ptr, int* __restrict__ fill,
                       int* __restrict__ csr_src) {
    int e = blockIdx.x * 256 + threadIdx.x;
    if (e < N_EDGES) {
        int d = dst[e];
        int pos = row_ptr[d] + atomicAdd(&fill[d], 1);
        csr_src[pos] = src[e];
    }
}

// ---------------- MFMA GEMM (qkv only): 128x128 tile, K-chunk 64, XOR-swizzled LDS ------
// EPI 0: qkv record per node = 128 u32 words (512 B):
//        words 0..63: q as bf16 pairs; word 64+i bytes = [k(2i),k(2i+1),v(2i),v(2i+1)] fp8
template <int EPI>
__global__ __launch_bounds__(256) void k_mm(
    const u16* __restrict__ A, int lda,
    const u16* __restrict__ BT,
    void* __restrict__ Cv, int ldc,
    int K,
    const float* __restrict__ bias,
    const float* __restrict__ prelu,
    const u16* __restrict__ resid,
    const float* __restrict__ g,
    const float* __restrict__ bb)
{
    __shared__ u16 smem[17408];
    u16* sA = smem;                 // 128 rows x 64 u16 (swizzled)
    u16* sB = smem + 128 * 64;
    u16* sC = smem;                 // epilogue overlay

    const int t = threadIdx.x;
    const int w = t >> 6;
    const int lane = t & 63;
    const int ln = lane & 15, q4 = lane >> 4;
    const int row0 = blockIdx.x * 128;
    const int cb = blockIdx.y * 128;

    f32x4 acc[2][8];
#pragma unroll
    for (int mt = 0; mt < 2; ++mt)
#pragma unroll
        for (int nt = 0; nt < 8; ++nt)
            acc[mt][nt] = (f32x4){0.f, 0.f, 0.f, 0.f};

    uint4 pa[4], pb[4];
#define LOAD_A(kc)                                                             \
    {                                                                          \
        _Pragma("unroll") for (int i = 0; i < 4; ++i) {                        \
            int u = i * 256 + t, r = u >> 3, k8 = (u & 7) * 8;                 \
            int row = row0 + r;                                                \
            uint4 val = make_uint4(0, 0, 0, 0);                                \
            if (row < N_NODES)                                                 \
                val = *reinterpret_cast<const uint4*>(A + (size_t)row * lda + (kc) + k8); \
            pa[i] = val;                                                       \
        }                                                                      \
    }
#define LOAD_B(kc)                                                             \
    {                                                                          \
        _Pragma("unroll") for (int i = 0; i < 4; ++i) {                        \
            int u = i * 256 + t, r = u >> 3, k8 = (u & 7) * 8;                 \
            pb[i] = *reinterpret_cast<const uint4*>(BT + (size_t)(cb + r) * K + (kc) + k8); \
        }                                                                      \
    }

    LOAD_A(0);
    LOAD_B(0);

    for (int kc = 0; kc < K; kc += 64) {
#pragma unroll
        for (int i = 0; i < 4; ++i) {
            int u = i * 256 + t, r = u >> 3, gi = u & 7;
            int off = (r * 8 + (gi ^ (r & 7))) * 8;
            *reinterpret_cast<uint4*>(&sA[off]) = pa[i];
            *reinterpret_cast<uint4*>(&sB[off]) = pb[i];
        }
        __syncthreads();
        if (kc + 64 < K) {
            LOAD_A(kc + 64);
            LOAD_B(kc + 64);
        }
#pragma unroll
        for (int ks = 0; ks < 2; ++ks) {
            const int gsw = ks * 4 + q4;
            const int rA0 = w * 32 + ln;
            const int rA1 = rA0 + 16;
            bf16x8 a0 = *reinterpret_cast<const bf16x8*>(&sA[(rA0 * 8 + (gsw ^ (rA0 & 7))) * 8]);
            bf16x8 a1 = *reinterpret_cast<const bf16x8*>(&sA[(rA1 * 8 + (gsw ^ (rA1 & 7))) * 8]);
#pragma unroll
            for (int nt = 0; nt < 8; ++nt) {
                const int rB = nt * 16 + ln;
                bf16x8 b = *reinterpret_cast<const bf16x8*>(&sB[(rB * 8 + (gsw ^ (rB & 7))) * 8]);
                acc[0][nt] = __builtin_amdgcn_mfma_f32_16x16x32_bf16(a0, b, acc[0][nt], 0, 0, 0);
                acc[1][nt] = __builtin_amdgcn_mfma_f32_16x16x32_bf16(a1, b, acc[1][nt], 0, 0, 0);
            }
        }
        __syncthreads();
    }
#undef LOAD_A
#undef LOAD_B

    {
#pragma unroll
        for (int mt = 0; mt < 2; ++mt)
#pragma unroll
            for (int nt = 0; nt < 8; ++nt)
#pragma unroll
                for (int j = 0; j < 4; ++j) {
                    float x = acc[mt][nt][j];
                    sC[(w * 32 + mt * 16 + q4 * 4 + j) * 136 + nt * 16 + ln] = f2bf(x);
                }
        __syncthreads();
        if (EPI == 0 && cb != 0) {
            // pack K (cb==128, even u16) or V (cb==256, odd u16) as fp8 e4m3 pairs
            u16* C = (u16*)Cv;
            const u32 vflag = (cb == 256) ? 1u : 0u;
#pragma unroll
            for (int i = 0; i < 32; ++i) {   // 128 rows * 64 pairs = 8192 units
                int u = i * 256 + t;
                int r = u >> 6, p = u & 63;
                int row = row0 + r;
                if (row < N_NODES) {
                    u32 pair = *reinterpret_cast<const u32*>(&sC[r * 136 + p * 2]);
                    int packed = __builtin_amdgcn_cvt_pk_fp8_f32(blo(pair), bhi(pair), 0, false);
                    C[(u32)row * 256u + 128u + (u32)p * 2u + vflag] = (u16)(packed & 0xffff);
                }
            }
        } else {
            u16* C = (u16*)Cv;
#pragma unroll
            for (int i = 0; i < 8; ++i) {
                int u = i * 256 + t;
                int r = u >> 4, c8 = (u & 15) * 8;
                int row = row0 + r;
                if (row < N_NODES) {
                    uint4 val = *reinterpret_cast<const uint4*>(&sC[r * 136 + c8]);
                    *reinterpret_cast<uint4*>(&C[(size_t)row * ldc + cb + c8]) = val;
                }
            }
        }
    }
}

// ---------------- fused FFN: out = LN(rst + PReLU(rst@W1+b1)@W2 + b2) ----------------
// One block per 128 rows. sA = rst tile (resident, also residual source).
// B operands come FRAG-LINEAR from L2: one coalesced 1KB load per (nt,ks) per wave,
// no LDS staging, no barriers in the chunk loop. sH is wave-private.
// K-order identical to the old mm1->mm2 chain => bitwise-identical output.
__global__ __launch_bounds__(256) void k_ffn(
    const u16* __restrict__ rstb,     // [N][128] bf16
    const u16* __restrict__ W1F,      // frag-linear, 65536 u16
    const u16* __restrict__ W2F,      // frag-linear, 65536 u16
    const float* __restrict__ b1,
    const float* __restrict__ prelu,
    const float* __restrict__ b2,
    const float* __restrict__ g,
    const float* __restrict__ bb,
    float* __restrict__ out)
{
    __shared__ u16 sA[16384];   // 128 x 128, swizzled
    __shared__ u16 sH[16384];   // 128 x 128, swizzled, wave-private rows

    const int t = threadIdx.x;
    const int w = t >> 6;
    const int lane = t & 63;
    const int ln = lane & 15, q4 = lane >> 4;
    const int row0 = blockIdx.x * 128;

    // stage sA: row r, granule gi (8 u16) -> (r*16 + (gi ^ (r&15))) * 8
#pragma unroll
    for (int i = 0; i < 8; ++i) {
        int u = i * 256 + t, r = u >> 4, gi = u & 15;
        int row = row0 + r;
        uint4 val = make_uint4(0, 0, 0, 0);
        if (row < N_NODES)
            val = *reinterpret_cast<const uint4*>(rstb + (size_t)row * 128 + gi * 8);
        *reinterpret_cast<uint4*>(&sA[(r * 16 + (gi ^ (r & 15))) * 8]) = val;
    }
    __syncthreads();

    const int rA0 = w * 32 + ln;
    const int rA1 = rA0 + 16;

    f32x4 acc2[2][8];
#pragma unroll
    for (int mt = 0; mt < 2; ++mt)
#pragma unroll
        for (int nt = 0; nt < 8; ++nt)
            acc2[mt][nt] = (f32x4){0.f, 0.f, 0.f, 0.f};

    for (int c = 0; c < 4; ++c) {
        // GEMM1: acc1 = sA @ W1[:, c*128..c*128+127]
        f32x4 acc1[2][8];
#pragma unroll
        for (int mt = 0; mt < 2; ++mt)
#pragma unroll
            for (int nt = 0; nt < 8; ++nt)
                acc1[mt][nt] = (f32x4){0.f, 0.f, 0.f, 0.f};
#pragma unroll
        for (int ks = 0; ks < 4; ++ks) {
            const int gsw = ks * 4 + q4;
            bf16x8 a0 = *reinterpret_cast<const bf16x8*>(&sA[(rA0 * 16 + (gsw ^ (rA0 & 15))) * 8]);
            bf16x8 a1 = *reinterpret_cast<const bf16x8*>(&sA[(rA1 * 16 + (gsw ^ (rA1 & 15))) * 8]);
#pragma unroll
            for (int nt = 0; nt < 8; ++nt) {
                bf16x8 b = *reinterpret_cast<const bf16x8*>(
                    W1F + (((size_t)(c * 32 + ks * 8 + nt)) << 9) + lane * 8);
                acc1[0][nt] = __builtin_amdgcn_mfma_f32_16x16x32_bf16(a0, b, acc1[0][nt], 0, 0, 0);
                acc1[1][nt] = __builtin_amdgcn_mfma_f32_16x16x32_bf16(a1, b, acc1[1][nt], 0, 0, 0);
            }
        }
        // bias + PReLU -> bf16 -> sH (wave-private rows; in-wave LDS ordering suffices)
#pragma unroll
        for (int mt = 0; mt < 2; ++mt)
#pragma unroll
            for (int nt = 0; nt < 8; ++nt) {
                const int col = nt * 16 + ln;
                const float bsv = b1[c * 128 + col];
                const float prv = prelu[c * 128 + col];
                const int gi = col >> 3;
#pragma unroll
                for (int j = 0; j < 4; ++j) {
                    float x = acc1[mt][nt][j] + bsv;
                    x = (x >= 0.f) ? x : prv * x;
                    const int row = w * 32 + mt * 16 + q4 * 4 + j;
                    sH[(row * 16 + (gi ^ (row & 15))) * 8 + (col & 7)] = f2bf(x);
                }
            }
        // GEMM2: acc2 += sH @ W2[c*128..c*128+127, :]
#pragma unroll
        for (int ks = 0; ks < 4; ++ks) {
            const int gsw = ks * 4 + q4;
            bf16x8 h0 = *reinterpret_cast<const bf16x8*>(&sH[(rA0 * 16 + (gsw ^ (rA0 & 15))) * 8]);
            bf16x8 h1 = *reinterpret_cast<const bf16x8*>(&sH[(rA1 * 16 + (gsw ^ (rA1 & 15))) * 8]);
#pragma unroll
            for (int nt = 0; nt < 8; ++nt) {
                bf16x8 b = *reinterpret_cast<const bf16x8*>(
                    W2F + (((size_t)(c * 32 + ks * 8 + nt)) << 9) + lane * 8);
                acc2[0][nt] = __builtin_amdgcn_mfma_f32_16x16x32_bf16(h0, b, acc2[0][nt], 0, 0, 0);
                acc2[1][nt] = __builtin_amdgcn_mfma_f32_16x16x32_bf16(h1, b, acc2[1][nt], 0, 0, 0);
            }
        }
    }

    // epilogue: + b2 + resid(sA) + row LayerNorm, fp32 out
    float bs[8], gv[8], bv[8];
#pragma unroll
    for (int nt = 0; nt < 8; ++nt) {
        int col = nt * 16 + ln;
        bs[nt] = b2[col];
        gv[nt] = g[col];
        bv[nt] = bb[col];
    }
#pragma unroll
    for (int mt = 0; mt < 2; ++mt)
#pragma unroll
        for (int j = 0; j < 4; ++j) {
            const int lrow = w * 32 + mt * 16 + q4 * 4 + j;
            const int row = row0 + lrow;
            const bool ok = row < N_NODES;
            float vals[8];
            float s = 0.f, ss = 0.f;
#pragma unroll
            for (int nt = 0; nt < 8; ++nt) {
                const int col = nt * 16 + ln;
                const int gi = col >> 3;
                float res = bf2f(sA[(lrow * 16 + (gi ^ (lrow & 15))) * 8 + (col & 7)]);
                float x = acc2[mt][nt][j] + bs[nt] + res;
                vals[nt] = x;
                s += x; ss += x * x;
            }
            s += __shfl_xor(s, 8, 16); ss += __shfl_xor(ss, 8, 16);
            s += __shfl_xor(s, 4, 16); ss += __shfl_xor(ss, 4, 16);
            s += __shfl_xor(s, 2, 16); ss += __shfl_xor(ss, 2, 16);
            s += __shfl_xor(s, 1, 16); ss += __shfl_xor(ss, 1, 16);
            float mu = s * (1.f / 128.f);
            float var = ss * (1.f / 128.f) - mu * mu;
            float rs = rsqrtf(var + 1e-5f);
            if (ok) {
#pragma unroll
                for (int nt = 0; nt < 8; ++nt)
                    out[(size_t)row * 128 + nt * 16 + ln] =
                        (vals[nt] - mu) * rs * gv[nt] + bv[nt];
            }
        }
}

// ---------------- attention: 1 wave/node, fp8 K/V, one u32 load/edge ----------
// Record: 128 u32/node. q words 0..63 bf16-pairs; word 64+lane = [k0 k1 v0 v1] fp8.
// Pipeline: csr 2-groups-ahead, A/B ping-pong.
__global__ __launch_bounds__(256) void k_attn(
    const u32* __restrict__ Q32, const float* __restrict__ feat,
    const int* __restrict__ row_ptr, const int* __restrict__ csr_src,
    const float* __restrict__ g, const float* __restrict__ bb,
    u16* __restrict__ rstb)
{
    const int w = threadIdx.x >> 6;
    const int lane = threadIdx.x & 63;
    const int n = blockIdx.x * 4 + w;
    if (n >= N_NODES) return;
    const float scale = 0.08838834764831845f;  // 1/sqrt(128)

    const u32 qp = Q32[(u32)n * 128u + (u32)lane];
    const float q0 = blo(qp), q1 = bhi(qp);
    const int e0 = row_ptr[n], e1 = row_ptr[n + 1];
    const u32 kvlane = 64u + (u32)lane;

    float l = 0.f, a0 = 0.f, a1 = 0.f;

#define LD4(S, KV)                                                                      \
    {                                                                                   \
        KV[0] = Q32[(u32)(S).x * 128u + kvlane];                                        \
        KV[1] = Q32[(u32)(S).y * 128u + kvlane];                                        \
        KV[2] = Q32[(u32)(S).z * 128u + kvlane];                                        \
        KV[3] = Q32[(u32)(S).w * 128u + kvlane];                                        \
    }
#define CG(KV)                                                                          \
    {                                                                                   \
        f32x2 k0 = __builtin_amdgcn_cvt_pk_f32_fp8((int)KV[0], false);                  \
        f32x2 k1 = __builtin_amdgcn_cvt_pk_f32_fp8((int)KV[1], false);                  \
        f32x2 k2 = __builtin_amdgcn_cvt_pk_f32_fp8((int)KV[2], false);                  \
        f32x2 k3 = __builtin_amdgcn_cvt_pk_f32_fp8((int)KV[3], false);                  \
        float p0 = k0.x * q0 + k0.y * q1;                                               \
        float p1 = k1.x * q0 + k1.y * q1;                                               \
        float p2 = k2.x * q0 + k2.y * q1;                                               \
        float p3 = k3.x * q0 + k3.y * q1;                                               \
        p0 += __shfl_xor(p0, 4, 8); p1 += __shfl_xor(p1, 4, 8);                         \
        p2 += __shfl_xor(p2, 4, 8); p3 += __shfl_xor(p3, 4, 8);                         \
        p0 += __shfl_xor(p0, 2, 8); p1 += __shfl_xor(p1, 2, 8);                         \
        p2 += __shfl_xor(p2, 2, 8); p3 += __shfl_xor(p3, 2, 8);                         \
        p0 += __shfl_xor(p0, 1, 8); p1 += __shfl_xor(p1, 1, 8);                         \
        p2 += __shfl_xor(p2, 1, 8); p3 += __shfl_xor(p3, 1, 8);                         \
        float ea = __expf(p0 * scale), eb = __expf(p1 * scale);                         \
        float ec = __expf(p2 * scale), ed = __expf(p3 * scale);                         \
        l += (ea + eb) + (ec + ed);                                                     \
        f32x2 v0 = __builtin_amdgcn_cvt_pk_f32_fp8((int)KV[0], true);                   \
        f32x2 v1 = __builtin_amdgcn_cvt_pk_f32_fp8((int)KV[1], true);                   \
        f32x2 v2 = __builtin_amdgcn_cvt_pk_f32_fp8((int)KV[2], true);                   \
        f32x2 v3 = __builtin_amdgcn_cvt_pk_f32_fp8((int)KV[3], true);                   \
        a0 += ea * v0.x + eb * v1.x + ec * v2.x + ed * v3.x;                            \
        a1 += ea * v0.y + eb * v1.y + ec * v2.y + ed * v3.y;                            \
    }

    int e = e0;
    int rem = e1 - e0;
    {
        int4 sA, sB;
        u32 kvA[4], kvB[4];
        if (rem >= 4) {
            sA = *reinterpret_cast<const int4*>(csr_src + e);
            LD4(sA, kvA);
            if (rem >= 8) {
                sB = *reinterpret_cast<const int4*>(csr_src + e + 4);
                while (true) {
                    if (rem >= 12) sA = *reinterpret_cast<const int4*>(csr_src + e + 8);
                    LD4(sB, kvB);
                    CG(kvA);
                    e += 4; rem -= 4;
                    if (rem < 8) { CG(kvB); e += 4; rem -= 4; break; }
                    if (rem >= 12) sB = *reinterpret_cast<const int4*>(csr_src + e + 8);
                    LD4(sA, kvA);
                    CG(kvB);
                    e += 4; rem -= 4;
                    if (rem < 8) { CG(kvA); e += 4; rem -= 4; break; }
                }
            } else {
                CG(kvA);
                e += 4; rem -= 4;
            }
        }
    }
    // tail: 0..3 edges
    for (; e < e1; ++e) {
        int s0 = csr_src[e];
        u32 kv = Q32[(u32)s0 * 128u + kvlane];
        f32x2 kf = __builtin_amdgcn_cvt_pk_f32_fp8((int)kv, false);
        float p0 = kf.x * q0 + kf.y * q1;
        p0 += __shfl_xor(p0, 4, 8);
        p0 += __shfl_xor(p0, 2, 8);
        p0 += __shfl_xor(p0, 1, 8);
        float ea = __expf(p0 * scale);
        f32x2 vf = __builtin_amdgcn_cvt_pk_f32_fp8((int)kv, true);
        l += ea;
        a0 += ea * vf.x;
        a1 += ea * vf.y;
    }
#undef LD4
#undef CG

    float inv = (l > 0.f) ? 1.f / l : 0.f;   // deg-0 node -> 0
    const int c2 = lane * 2;
    const float2 fr = *reinterpret_cast<const float2*>(feat + (size_t)n * 128 + c2);
    float x0 = a0 * inv + fr.x;
    float x1 = a1 * inv + fr.y;

    float sum = x0 + x1, sq = x0 * x0 + x1 * x1;
#pragma unroll
    for (int off = 32; off >= 1; off >>= 1) {
        sum += __shfl_xor(sum, off, 64);
        sq += __shfl_xor(sq, off, 64);
    }
    float mu = sum * (1.f / 128.f);
    float var = sq * (1.f / 128.f) - mu * mu;
    float rs = rsqrtf(var + 1e-5f);
    float y0 = (x0 - mu) * rs * g[c2] + bb[c2];
    float y1 = (x1 - mu) * rs * g[c2 + 1] + bb[c2 + 1];
    reinterpret_cast<u32*>(rstb)[(size_t)n * 64 + lane] = pack2(y0, y1);
}

extern "C" void kernel_launch(void* const* d_in, const int* in_sizes, int n_in,
                              void* d_out, int out_size, void* d_ws, size_t ws_size,
                              hipStream_t stream)
{
    const float* feat = (const float*)d_in[0];
    const int* src    = (const int*)d_in[1];
    const int* dst    = (const int*)d_in[2];
    const float* Wq   = (const float*)d_in[3];
    const float* Wk   = (const float*)d_in[4];
    const float* Wv   = (const float*)d_in[5];
    const float* ln_g = (const float*)d_in[6];
    const float* ln_b = (const float*)d_in[7];
    const float* W1   = (const float*)d_in[8];
    const float* b1   = (const float*)d_in[9];
    const float* pa   = (const float*)d_in[10];
    const float* W2   = (const float*)d_in[11];
    const float* b2   = (const float*)d_in[12];

    u16* qkv   = (u16*)d_ws;                           // 50000*256 u16 used (region reserves 384)
    u16* h     = qkv + (size_t)N_NODES * 384;          // region kept for layout stability
    u16* featb = h;                                    // 50000*128, dead before ffn
    u16* rstb  = h + (size_t)N_NODES * 512;            // 50000*128
    u16* WT    = rstb + (size_t)N_NODES * 128;         // 180224
    u16* BqkvT = WT;
    u16* W1F   = WT + 49152;
    u16* W2F   = WT + 114688;
    int* counts  = (int*)(WT + 180224);
    int* fill    = counts + N_NODES;
    int* row_ptr = fill + N_NODES;
    int* csr_src = row_ptr + N_NODES + 1;
    int* bsum    = csr_src + N_EDGES;

    // zero counts+fill first, then fused prep+hist
    hipMemsetAsync(counts, 0, sizeof(int) * 2 * N_NODES, stream);
    k_prep<<<(PH_TOTAL + 255) / 256, 256, 0, stream>>>(
        feat, featb, Wq, Wk, Wv, W1, W2, WT, dst, counts);

    // CSR: bsum -> fused scan+fill of row_ptr -> edge fill
    k_bsum<<<NB, 256, 0, stream>>>(counts, bsum);
    k_bfill<<<NB, 256, 0, stream>>>(counts, bsum, row_ptr);
    k_fill<<<(N_EDGES + 255) / 256, 256, 0, stream>>>(src, dst, row_ptr, fill, csr_src);

    const int MBK = (N_NODES + 127) / 128;   // 391

    dim3 gqkv(MBK, 3);
    k_mm<0><<<gqkv, 256, 0, stream>>>(featb, 128, BqkvT, qkv, 256, 128,
                                      nullptr, nullptr, nullptr, nullptr, nullptr);

    k_attn<<<(N_NODES + 3) / 4, 256, 0, stream>>>((const u32*)qkv, feat, row_ptr, csr_src,
                                                  ln_g, ln_b, rstb);

    k_ffn<<<MBK, 256, 0, stream>>>(rstb, W1F, W2F, b1, pa, b2, ln_g, ln_b,
                                   (float*)d_out);
}

// Round 10
// 301.651 us; speedup vs baseline: 1.2038x; 1.2023x over previous
//
#include <hip/hip_runtime.h>

#define N_NODES 50000
#define N_EDGES 640000
#define F 128
#define DFF 512
#define NB 196   // ceil(N_NODES/256)

using u32 = unsigned int;
using u16 = unsigned short;

typedef __bf16 bf16x8 __attribute__((ext_vector_type(8)));
typedef float f32x4 __attribute__((ext_vector_type(4)));
typedef float f32x2 __attribute__((ext_vector_type(2)));

__device__ __forceinline__ float bf2f(u16 u) {
    return __uint_as_float(((u32)u) << 16);
}
__device__ __forceinline__ float blo(u32 p) { return __uint_as_float(p << 16); }
__device__ __forceinline__ float bhi(u32 p) { return __uint_as_float(p & 0xffff0000u); }
__device__ __forceinline__ u16 f2bf(float f) {
    u32 u = __float_as_uint(f);
    u += 0x7fffu + ((u >> 16) & 1u);   // RNE
    return (u16)(u >> 16);
}
__device__ __forceinline__ u32 pack2(float a, float b) {
    return (u32)f2bf(a) | ((u32)f2bf(b) << 16);
}

// ---------------- fused prep: feat->bf16 + weights->bf16^T + degree histogram ----------
#define FEAT_UNITS (N_NODES * F / 4)   // 1,600,000 float4 units
#define PH_TOTAL (FEAT_UNITS + 180224 + N_EDGES)
__global__ void k_prep(const float* __restrict__ feat, u16* __restrict__ featb,
                       const float* __restrict__ Wq, const float* __restrict__ Wk,
                       const float* __restrict__ Wv, const float* __restrict__ W1,
                       const float* __restrict__ W2, u16* __restrict__ WT,
                       const int* __restrict__ dst, int* __restrict__ cnt) {
    int idx = blockIdx.x * 256 + threadIdx.x;
    if (idx < FEAT_UNITS) {
        float4 v = reinterpret_cast<const float4*>(feat)[idx];
        uint2 p;
        p.x = pack2(v.x, v.y);
        p.y = pack2(v.z, v.w);
        reinterpret_cast<uint2*>(featb)[idx] = p;
        return;
    }
    int wi = idx - FEAT_UNITS;
    if (wi < 180224) {
        if (wi < 49152) {
            int mi = wi >> 14;
            int local = wi & 16383;
            const float* W = (mi == 0) ? Wq : ((mi == 1) ? Wk : Wv);
            int n = local >> 7, k = local & 127;
            WT[wi] = f2bf(W[(size_t)k * 128 + n]);
        } else if (wi < 114688) {
            int local = wi - 49152;
            int n = local >> 7, k = local & 127;
            WT[wi] = f2bf(W1[(size_t)k * 512 + n]);
        } else {
            int local = wi - 114688;
            int n = local >> 9, k = local & 511;
            WT[wi] = f2bf(W2[(size_t)k * 128 + n]);
        }
        return;
    }
    int e = wi - 180224;
    if (e < N_EDGES) atomicAdd(&cnt[dst[e]], 1);
}

// ---------------- CSR build ----------------
__global__ void k_bsum(const int* __restrict__ counts, int* __restrict__ bsum) {
    int i = blockIdx.x * 256 + threadIdx.x;
    int v = (i < N_NODES) ? counts[i] : 0;
#pragma unroll
    for (int off = 32; off >= 1; off >>= 1) v += __shfl_xor(v, off, 64);
    __shared__ int ws[4];
    int lane = threadIdx.x & 63, wid = threadIdx.x >> 6;
    if (lane == 0) ws[wid] = v;
    __syncthreads();
    if (threadIdx.x == 0) bsum[blockIdx.x] = ws[0] + ws[1] + ws[2] + ws[3];
}

// fused: block-scan of bsum (196 entries) in-LDS + per-chunk scan of counts
__global__ void k_bfill(const int* __restrict__ counts, const int* __restrict__ bsum,
                        int* __restrict__ row_ptr) {
    int b = blockIdx.x, t = threadIdx.x;
    int lane = t & 63, wid = t >> 6;
    __shared__ int ws[4];
    __shared__ int sboff[256];

    int bv = (t < NB) ? bsum[t] : 0;
    int bincl = bv;
#pragma unroll
    for (int off = 1; off < 64; off <<= 1) {
        int u = __shfl_up(bincl, off, 64);
        if (lane >= off) bincl += u;
    }
    if (lane == 63) ws[wid] = bincl;
    __syncthreads();
    int bwo = 0;
#pragma unroll
    for (int j = 0; j < 4; ++j) if (j < wid) bwo += ws[j];
    sboff[t] = bwo + bincl - bv;
    __syncthreads();
    const int boff = sboff[b];

    int i = b * 256 + t;
    int v = (i < N_NODES) ? counts[i] : 0;
    int incl = v;
#pragma unroll
    for (int off = 1; off < 64; off <<= 1) {
        int u = __shfl_up(incl, off, 64);
        if (lane >= off) incl += u;
    }
    if (lane == 63) ws[wid] = incl;
    __syncthreads();
    int wo = 0;
#pragma unroll
    for (int j = 0; j < 4; ++j) if (j < wid) wo += ws[j];
    if (i < N_NODES) row_ptr[i] = boff + wo + incl - v;
    if (i == 0) row_ptr[N_NODES] = N_EDGES;
}

__global__ void k_fill(const int* __restrict__ src, const int* __restrict__ dst,
                       const int* __restrict__ row_ptr, int* __restrict__ fill,
                       int* __restrict__ csr_src) {
    int e = blockIdx.x * 256 + threadIdx.x;
    if (e < N_EDGES) {
        int d = dst[e];
        int pos = row_ptr[d] + atomicAdd(&fill[d], 1);
        csr_src[pos] = src[e];
    }
}

// ---------------- MFMA GEMM: 128x128 tile, K-chunk 64 reg-dbuf, XOR-swizzled LDS ----------
// EPI 0: qkv record per node = 128 u32 words (512 B):
//        words 0..63: q as bf16 pairs; word 64+i bytes = [k(2i),k(2i+1),v(2i),v(2i+1)] fp8
// EPI 1: +bias, PReLU, bf16 store via LDS-staged coalesced uint4 (ffn1 -> h)
// EPI 2: +bias +resid(bf16), row LayerNorm, fp32 store (ffn2 -> out)
template <int EPI>
__global__ __launch_bounds__(256) void k_mm(
    const u16* __restrict__ A, int lda,
    const u16* __restrict__ BT,
    void* __restrict__ Cv, int ldc,
    int K,
    const float* __restrict__ bias,
    const float* __restrict__ prelu,
    const u16* __restrict__ resid,
    const float* __restrict__ g,
    const float* __restrict__ bb)
{
    __shared__ u16 smem[17408];
    u16* sA = smem;                 // 128 rows x 64 u16 (swizzled)
    u16* sB = smem + 128 * 64;
    u16* sC = smem;                 // epilogue overlay

    const int t = threadIdx.x;
    const int w = t >> 6;
    const int lane = t & 63;
    const int ln = lane & 15, q4 = lane >> 4;
    const int row0 = blockIdx.x * 128;
    const int cb = blockIdx.y * 128;

    f32x4 acc[2][8];
#pragma unroll
    for (int mt = 0; mt < 2; ++mt)
#pragma unroll
        for (int nt = 0; nt < 8; ++nt)
            acc[mt][nt] = (f32x4){0.f, 0.f, 0.f, 0.f};

    uint4 pa[4], pb[4];
#define LOAD_A(kc)                                                             \
    {                                                                          \
        _Pragma("unroll") for (int i = 0; i < 4; ++i) {                        \
            int u = i * 256 + t, r = u >> 3, k8 = (u & 7) * 8;                 \
            int row = row0 + r;                                                \
            uint4 val = make_uint4(0, 0, 0, 0);                                \
            if (row < N_NODES)                                                 \
                val = *reinterpret_cast<const uint4*>(A + (size_t)row * lda + (kc) + k8); \
            pa[i] = val;                                                       \
        }                                                                      \
    }
#define LOAD_B(kc)                                                             \
    {                                                                          \
        _Pragma("unroll") for (int i = 0; i < 4; ++i) {                        \
            int u = i * 256 + t, r = u >> 3, k8 = (u & 7) * 8;                 \
            pb[i] = *reinterpret_cast<const uint4*>(BT + (size_t)(cb + r) * K + (kc) + k8); \
        }                                                                      \
    }

    LOAD_A(0);
    LOAD_B(0);

    for (int kc = 0; kc < K; kc += 64) {
#pragma unroll
        for (int i = 0; i < 4; ++i) {
            int u = i * 256 + t, r = u >> 3, gi = u & 7;
            int off = (r * 8 + (gi ^ (r & 7))) * 8;
            *reinterpret_cast<uint4*>(&sA[off]) = pa[i];
            *reinterpret_cast<uint4*>(&sB[off]) = pb[i];
        }
        __syncthreads();
        if (kc + 64 < K) {
            LOAD_A(kc + 64);
            LOAD_B(kc + 64);
        }
#pragma unroll
        for (int ks = 0; ks < 2; ++ks) {
            const int gsw = ks * 4 + q4;
            const int rA0 = w * 32 + ln;
            const int rA1 = rA0 + 16;
            bf16x8 a0 = *reinterpret_cast<const bf16x8*>(&sA[(rA0 * 8 + (gsw ^ (rA0 & 7))) * 8]);
            bf16x8 a1 = *reinterpret_cast<const bf16x8*>(&sA[(rA1 * 8 + (gsw ^ (rA1 & 7))) * 8]);
#pragma unroll
            for (int nt = 0; nt < 8; ++nt) {
                const int rB = nt * 16 + ln;
                bf16x8 b = *reinterpret_cast<const bf16x8*>(&sB[(rB * 8 + (gsw ^ (rB & 7))) * 8]);
                acc[0][nt] = __builtin_amdgcn_mfma_f32_16x16x32_bf16(a0, b, acc[0][nt], 0, 0, 0);
                acc[1][nt] = __builtin_amdgcn_mfma_f32_16x16x32_bf16(a1, b, acc[1][nt], 0, 0, 0);
            }
        }
        __syncthreads();
    }
#undef LOAD_A
#undef LOAD_B

    if (EPI == 0 || EPI == 1) {
        float bs[8], pr[8];
        if (EPI == 1) {
#pragma unroll
            for (int nt = 0; nt < 8; ++nt) {
                int col = cb + nt * 16 + ln;
                bs[nt] = bias[col];
                pr[nt] = prelu[col];
            }
        }
#pragma unroll
        for (int mt = 0; mt < 2; ++mt)
#pragma unroll
            for (int nt = 0; nt < 8; ++nt)
#pragma unroll
                for (int j = 0; j < 4; ++j) {
                    float x = acc[mt][nt][j];
                    if (EPI == 1) {
                        x += bs[nt];
                        x = (x >= 0.f) ? x : pr[nt] * x;
                    }
                    sC[(w * 32 + mt * 16 + q4 * 4 + j) * 136 + nt * 16 + ln] = f2bf(x);
                }
        __syncthreads();
        if (EPI == 0 && cb != 0) {
            // pack K (cb==128, even u16) or V (cb==256, odd u16) as fp8 e4m3 pairs
            u16* C = (u16*)Cv;
            const u32 vflag = (cb == 256) ? 1u : 0u;
#pragma unroll
            for (int i = 0; i < 32; ++i) {   // 128 rows * 64 pairs = 8192 units
                int u = i * 256 + t;
                int r = u >> 6, p = u & 63;
                int row = row0 + r;
                if (row < N_NODES) {
                    u32 pair = *reinterpret_cast<const u32*>(&sC[r * 136 + p * 2]);
                    int packed = __builtin_amdgcn_cvt_pk_fp8_f32(blo(pair), bhi(pair), 0, false);
                    C[(u32)row * 256u + 128u + (u32)p * 2u + vflag] = (u16)(packed & 0xffff);
                }
            }
        } else {
            u16* C = (u16*)Cv;
#pragma unroll
            for (int i = 0; i < 8; ++i) {
                int u = i * 256 + t;
                int r = u >> 4, c8 = (u & 15) * 8;
                int row = row0 + r;
                if (row < N_NODES) {
                    uint4 val = *reinterpret_cast<const uint4*>(&sC[r * 136 + c8]);
                    *reinterpret_cast<uint4*>(&C[(size_t)row * ldc + cb + c8]) = val;
                }
            }
        }
    } else {
        // bias + resid(bf16) + row LayerNorm, fp32 out. Block covers all 128 cols (cb==0).
        float* C = (float*)Cv;
        float bs[8], gv[8], bv[8];
#pragma unroll
        for (int nt = 0; nt < 8; ++nt) {
            int col = nt * 16 + ln;
            bs[nt] = bias[col];
            gv[nt] = g[col];
            bv[nt] = bb[col];
        }
#pragma unroll
        for (int mt = 0; mt < 2; ++mt)
#pragma unroll
            for (int j = 0; j < 4; ++j) {
                int row = row0 + w * 32 + mt * 16 + q4 * 4 + j;
                bool ok = row < N_NODES;
                float vals[8];
                float s = 0.f, ss = 0.f;
#pragma unroll
                for (int nt = 0; nt < 8; ++nt) {
                    float x = acc[mt][nt][j] + bs[nt];
                    if (ok) x += bf2f(resid[(size_t)row * 128 + nt * 16 + ln]);
                    vals[nt] = x;
                    s += x; ss += x * x;
                }
                s += __shfl_xor(s, 8, 16); ss += __shfl_xor(ss, 8, 16);
                s += __shfl_xor(s, 4, 16); ss += __shfl_xor(ss, 4, 16);
                s += __shfl_xor(s, 2, 16); ss += __shfl_xor(ss, 2, 16);
                s += __shfl_xor(s, 1, 16); ss += __shfl_xor(ss, 1, 16);
                float mu = s * (1.f / 128.f);
                float var = ss * (1.f / 128.f) - mu * mu;
                float rs = rsqrtf(var + 1e-5f);
                if (ok) {
#pragma unroll
                    for (int nt = 0; nt < 8; ++nt)
                        C[(size_t)row * 128 + nt * 16 + ln] =
                            (vals[nt] - mu) * rs * gv[nt] + bv[nt];
                }
            }
    }
}

// ---------------- attention: 1 wave/node, fp8 K/V, one u32 load/edge ----------
// Record: 128 u32/node. q words 0..63 bf16-pairs; word 64+lane = [k0 k1 v0 v1] fp8.
// Pipeline: csr 2-groups-ahead, A/B ping-pong.
__global__ __launch_bounds__(256) void k_attn(
    const u32* __restrict__ Q32, const float* __restrict__ feat,
    const int* __restrict__ row_ptr, const int* __restrict__ csr_src,
    const float* __restrict__ g, const float* __restrict__ bb,
    u16* __restrict__ rstb)
{
    const int w = threadIdx.x >> 6;
    const int lane = threadIdx.x & 63;
    const int n = blockIdx.x * 4 + w;
    if (n >= N_NODES) return;
    const float scale = 0.08838834764831845f;  // 1/sqrt(128)

    const u32 qp = Q32[(u32)n * 128u + (u32)lane];
    const float q0 = blo(qp), q1 = bhi(qp);
    const int e0 = row_ptr[n], e1 = row_ptr[n + 1];
    const u32 kvlane = 64u + (u32)lane;

    float l = 0.f, a0 = 0.f, a1 = 0.f;

#define LD4(S, KV)                                                                      \
    {                                                                                   \
        KV[0] = Q32[(u32)(S).x * 128u + kvlane];                                        \
        KV[1] = Q32[(u32)(S).y * 128u + kvlane];                                        \
        KV[2] = Q32[(u32)(S).z * 128u + kvlane];                                        \
        KV[3] = Q32[(u32)(S).w * 128u + kvlane];                                        \
    }
#define CG(KV)                                                                          \
    {                                                                                   \
        f32x2 k0 = __builtin_amdgcn_cvt_pk_f32_fp8((int)KV[0], false);                  \
        f32x2 k1 = __builtin_amdgcn_cvt_pk_f32_fp8((int)KV[1], false);                  \
        f32x2 k2 = __builtin_amdgcn_cvt_pk_f32_fp8((int)KV[2], false);                  \
        f32x2 k3 = __builtin_amdgcn_cvt_pk_f32_fp8((int)KV[3], false);                  \
        float p0 = k0.x * q0 + k0.y * q1;                                               \
        float p1 = k1.x * q0 + k1.y * q1;                                               \
        float p2 = k2.x * q0 + k2.y * q1;                                               \
        float p3 = k3.x * q0 + k3.y * q1;                                               \
        p0 += __shfl_xor(p0, 4, 8); p1 += __shfl_xor(p1, 4, 8);                         \
        p2 += __shfl_xor(p2, 4, 8); p3 += __shfl_xor(p3, 4, 8);                         \
        p0 += __shfl_xor(p0, 2, 8); p1 += __shfl_xor(p1, 2, 8);                         \
        p2 += __shfl_xor(p2, 2, 8); p3 += __shfl_xor(p3, 2, 8);                         \
        p0 += __shfl_xor(p0, 1, 8); p1 += __shfl_xor(p1, 1, 8);                         \
        p2 += __shfl_xor(p2, 1, 8); p3 += __shfl_xor(p3, 1, 8);                         \
        float ea = __expf(p0 * scale), eb = __expf(p1 * scale);                         \
        float ec = __expf(p2 * scale), ed = __expf(p3 * scale);                         \
        l += (ea + eb) + (ec + ed);                                                     \
        f32x2 v0 = __builtin_amdgcn_cvt_pk_f32_fp8((int)KV[0], true);                   \
        f32x2 v1 = __builtin_amdgcn_cvt_pk_f32_fp8((int)KV[1], true);                   \
        f32x2 v2 = __builtin_amdgcn_cvt_pk_f32_fp8((int)KV[2], true);                   \
        f32x2 v3 = __builtin_amdgcn_cvt_pk_f32_fp8((int)KV[3], true);                   \
        a0 += ea * v0.x + eb * v1.x + ec * v2.x + ed * v3.x;                            \
        a1 += ea * v0.y + eb * v1.y + ec * v2.y + ed * v3.y;                            \
    }

    int e = e0;
    int rem = e1 - e0;
    {
        int4 sA, sB;
        u32 kvA[4], kvB[4];
        if (rem >= 4) {
            sA = *reinterpret_cast<const int4*>(csr_src + e);
            LD4(sA, kvA);
            if (rem >= 8) {
                sB = *reinterpret_cast<const int4*>(csr_src + e + 4);
                while (true) {
                    if (rem >= 12) sA = *reinterpret_cast<const int4*>(csr_src + e + 8);
                    LD4(sB, kvB);
                    CG(kvA);
                    e += 4; rem -= 4;
                    if (rem < 8) { CG(kvB); e += 4; rem -= 4; break; }
                    if (rem >= 12) sB = *reinterpret_cast<const int4*>(csr_src + e + 8);
                    LD4(sA, kvA);
                    CG(kvB);
                    e += 4; rem -= 4;
                    if (rem < 8) { CG(kvA); e += 4; rem -= 4; break; }
                }
            } else {
                CG(kvA);
                e += 4; rem -= 4;
            }
        }
    }
    // tail: 0..3 edges
    for (; e < e1; ++e) {
        int s0 = csr_src[e];
        u32 kv = Q32[(u32)s0 * 128u + kvlane];
        f32x2 kf = __builtin_amdgcn_cvt_pk_f32_fp8((int)kv, false);
        float p0 = kf.x * q0 + kf.y * q1;
        p0 += __shfl_xor(p0, 4, 8);
        p0 += __shfl_xor(p0, 2, 8);
        p0 += __shfl_xor(p0, 1, 8);
        float ea = __expf(p0 * scale);
        f32x2 vf = __builtin_amdgcn_cvt_pk_f32_fp8((int)kv, true);
        l += ea;
        a0 += ea * vf.x;
        a1 += ea * vf.y;
    }
#undef LD4
#undef CG

    float inv = (l > 0.f) ? 1.f / l : 0.f;   // deg-0 node -> 0
    const int c2 = lane * 2;
    const float2 fr = *reinterpret_cast<const float2*>(feat + (size_t)n * 128 + c2);
    float x0 = a0 * inv + fr.x;
    float x1 = a1 * inv + fr.y;

    float sum = x0 + x1, sq = x0 * x0 + x1 * x1;
#pragma unroll
    for (int off = 32; off >= 1; off >>= 1) {
        sum += __shfl_xor(sum, off, 64);
        sq += __shfl_xor(sq, off, 64);
    }
    float mu = sum * (1.f / 128.f);
    float var = sq * (1.f / 128.f) - mu * mu;
    float rs = rsqrtf(var + 1e-5f);
    float y0 = (x0 - mu) * rs * g[c2] + bb[c2];
    float y1 = (x1 - mu) * rs * g[c2 + 1] + bb[c2 + 1];
    reinterpret_cast<u32*>(rstb)[(size_t)n * 64 + lane] = pack2(y0, y1);
}

extern "C" void kernel_launch(void* const* d_in, const int* in_sizes, int n_in,
                              void* d_out, int out_size, void* d_ws, size_t ws_size,
                              hipStream_t stream)
{
    const float* feat = (const float*)d_in[0];
    const int* src    = (const int*)d_in[1];
    const int* dst    = (const int*)d_in[2];
    const float* Wq   = (const float*)d_in[3];
    const float* Wk   = (const float*)d_in[4];
    const float* Wv   = (const float*)d_in[5];
    const float* ln_g = (const float*)d_in[6];
    const float* ln_b = (const float*)d_in[7];
    const float* W1   = (const float*)d_in[8];
    const float* b1   = (const float*)d_in[9];
    const float* pa   = (const float*)d_in[10];
    const float* W2   = (const float*)d_in[11];
    const float* b2   = (const float*)d_in[12];

    u16* qkv   = (u16*)d_ws;                           // 50000*256 u16 used (region reserves 384)
    u16* h     = qkv + (size_t)N_NODES * 384;          // region kept for layout stability
    u16* featb = h;                                    // 50000*128, dead before h written
    u16* rstb  = h + (size_t)N_NODES * 512;            // 50000*128
    u16* WT    = rstb + (size_t)N_NODES * 128;         // 180224
    u16* BqkvT = WT;
    u16* W1T   = WT + 49152;
    u16* W2T   = WT + 114688;
    int* counts  = (int*)(WT + 180224);
    int* fill    = counts + N_NODES;
    int* row_ptr = fill + N_NODES;
    int* csr_src = row_ptr + N_NODES + 1;
    int* bsum    = csr_src + N_EDGES;

    // zero counts+fill first, then fused prep+hist
    hipMemsetAsync(counts, 0, sizeof(int) * 2 * N_NODES, stream);
    k_prep<<<(PH_TOTAL + 255) / 256, 256, 0, stream>>>(
        feat, featb, Wq, Wk, Wv, W1, W2, WT, dst, counts);

    // CSR: bsum -> fused scan+fill of row_ptr -> edge fill
    k_bsum<<<NB, 256, 0, stream>>>(counts, bsum);
    k_bfill<<<NB, 256, 0, stream>>>(counts, bsum, row_ptr);
    k_fill<<<(N_EDGES + 255) / 256, 256, 0, stream>>>(src, dst, row_ptr, fill, csr_src);

    const int MBK = (N_NODES + 127) / 128;   // 391

    dim3 gqkv(MBK, 3);
    k_mm<0><<<gqkv, 256, 0, stream>>>(featb, 128, BqkvT, qkv, 256, 128,
                                      nullptr, nullptr, nullptr, nullptr, nullptr);

    k_attn<<<(N_NODES + 3) / 4, 256, 0, stream>>>((const u32*)qkv, feat, row_ptr, csr_src,
                                                  ln_g, ln_b, rstb);

    dim3 gf1(MBK, 4);
    k_mm<1><<<gf1, 256, 0, stream>>>(rstb, 128, W1T, h, 512, 128,
                                     b1, pa, nullptr, nullptr, nullptr);

    dim3 gf2(MBK, 1);
    k_mm<2><<<gf2, 256, 0, stream>>>(h, 512, W2T, d_out, 128, 512,
                                     b2, nullptr, rstb, ln_g, ln_b);
}